// Round 6
// baseline (211.489 us; speedup 1.0000x reference)
//
#include <hip/hip_runtime.h>
#include <hip/hip_bf16.h>
#include <math.h>

// B,T,E,WIN,OC,VOCAB = 256,2048,128,5,128,50000
#define B_   256
#define T_   2048
#define E_   128
#define WIN_ 5
#define PAD_ 2
#define OC_  128
#define VOCAB1 50001
#define TT   64                   // tokens per score-block
#define REAL_ROWS (TT + WIN_ - 1) // 68 rows incl. halo
#define ROWS 80                   // padded to 5 m-tiles of 16
#define ASTR 136                  // LDS row stride (bf16): 272B -> 2-way alias = free
#define MCH  8                    // chunks of 16 tokens per wave in gemm_max

#define NTAB_CH (VOCAB1 * E_ / 8) // 800016 short8 chunks

typedef __attribute__((ext_vector_type(8))) short short8;
typedef __attribute__((ext_vector_type(4))) float floatx4;

static __device__ __forceinline__ short f2bf(float f) {
    union { __hip_bfloat16 h; short s; } u;
    u.h = __float2bfloat16(f);
    return u.s;
}

__device__ __forceinline__ void atomicMaxFloat(float* addr, float v) {
    // works with 0xFFFFFFFF init pattern on both paths
    if (v >= 0.0f) atomicMax((int*)addr, __float_as_int(v));
    else           atomicMin((unsigned int*)addr, __float_as_uint(v));
}

__device__ __forceinline__ void conv_chunk(long i, const float* __restrict__ emb,
                                           const float* __restrict__ cnn_w,
                                           const float* __restrict__ att_w,
                                           short* __restrict__ tab, short* __restrict__ wsw,
                                           short* __restrict__ wsatt) {
    const float* src;
    short* dst;
    if (i < NTAB_CH) { src = emb; dst = tab; }
    else if ((i -= NTAB_CH) < OC_ * E_ / 8) { src = cnn_w; dst = wsw; }
    else if ((i -= OC_ * E_ / 8) < WIN_ * E_ / 8) { src = att_w; dst = wsatt; }
    else return;
    const float4* s = (const float4*)src + (size_t)i * 2;
    float4 a = s[0], b = s[1];
    short8 o = { f2bf(a.x), f2bf(a.y), f2bf(a.z), f2bf(a.w),
                 f2bf(b.x), f2bf(b.y), f2bf(b.z), f2bf(b.w) };
    *(short8*)(dst + (size_t)i * 8) = o;
}

// ---- prep: bf16 table + cnn_w + att_w into ws (2 chunks/thread) ----
__global__ void prep_full(const float* __restrict__ emb, const float* __restrict__ cnn_w,
                          const float* __restrict__ att_w,
                          short* __restrict__ tab, short* __restrict__ wsw,
                          short* __restrict__ wsatt) {
    long i = (long)(blockIdx.x * 256 + threadIdx.x) * 2;
    conv_chunk(i,     emb, cnn_w, att_w, tab, wsw, wsatt);
    conv_chunk(i + 1, emb, cnn_w, att_w, tab, wsw, wsatt);
}

// =====================  Kernel S: scores[B,T]  =====================
__launch_bounds__(256, 4)
__global__ void score_kernel(const int* __restrict__ x,
                             const short* __restrict__ tab,
                             const float* __restrict__ att_b_p,
                             const short* __restrict__ wsatt,
                             float* __restrict__ scores) {
    __shared__ short sh_a[ROWS * ASTR];     // 21760 B
    __shared__ short sh_att[16 * ASTR];     // 4352 B
    __shared__ float sh_r[ROWS * 8];        // 2560 B
    __shared__ int   sh_idx[ROWS];

    const int tid  = threadIdx.x;
    const int lane = tid & 63;
    const int w    = tid >> 6;
    const int b    = blockIdx.y;
    const int t0   = blockIdx.x * TT;
    const int l15  = lane & 15;
    const int quad = lane >> 4;
    const int rbase = tid >> 4;
    const int c     = tid & 15;

    if (tid < ROWS) {
        int gt = t0 + tid - PAD_;
        sh_idx[tid] = (tid < REAL_ROWS && gt >= 0 && gt < T_) ? x[b * T_ + gt] : -1;
    }
    {
        int o = tid >> 4, cc = tid & 15;
        short8 v = (short8){0,0,0,0,0,0,0,0};
        if (o < WIN_) v = *(const short8*)(wsatt + o * E_ + cc * 8);
        *(short8*)(&sh_att[o * ASTR + cc * 8]) = v;
    }
    __syncthreads();

    #pragma unroll
    for (int k = 0; k < 5; k++) {
        int row = rbase + 16 * k;
        int idx = sh_idx[row];
        short8 v = (short8){0,0,0,0,0,0,0,0};
        if (idx >= 0) v = *(const short8*)(tab + (size_t)idx * E_ + c * 8);
        *(short8*)(&sh_a[row * ASTR + c * 8]) = v;
    }
    __syncthreads();

    for (int mt = w; mt < 5; mt += 4) {
        floatx4 acc = (floatx4){0.f, 0.f, 0.f, 0.f};
        #pragma unroll
        for (int ks = 0; ks < 4; ks++) {
            short8 a  = *(const short8*)(&sh_a[(mt * 16 + l15) * ASTR + ks * 32 + quad * 8]);
            short8 bs = *(const short8*)(&sh_att[l15 * ASTR + ks * 32 + quad * 8]);
            acc = __builtin_amdgcn_mfma_f32_16x16x32_bf16(a, bs, acc, 0, 0, 0);
        }
        if (l15 < 8) {
            #pragma unroll
            for (int r = 0; r < 4; r++)
                sh_r[(mt * 16 + quad * 4 + r) * 8 + l15] = acc[r];
        }
    }
    __syncthreads();

    if (tid < TT) {
        float s = att_b_p[0];
        #pragma unroll
        for (int k = 0; k < WIN_; k++) s += sh_r[(tid + k) * 8 + k];
        scores[b * T_ + t0 + tid] = 1.0f / (1.0f + __expf(-s));
    }
}

// ============  Kernel M: barrier-free, LDS-free GEMM+max  ============
// wave = (tsub, colhalf h); handles 8 chunks of 16 tokens x 64 cols.
// Col-half pairs (w and w+2) read identical A rows -> L1 dedup.
__launch_bounds__(256, 3)
__global__ void gemm_max(const int* __restrict__ x,
                         const short* __restrict__ tab,
                         const float* __restrict__ scores,
                         const short* __restrict__ wsw,
                         const float* __restrict__ cnn_b,
                         float* __restrict__ out) {
    const int tid  = threadIdx.x;
    const int lane = tid & 63;
    const int w    = tid >> 6;
    const int tsub = w & 1;
    const int h    = w >> 1;
    const int b    = blockIdx.y;
    const int tbase = blockIdx.x * 256 + tsub * 128;
    const int l15  = lane & 15;
    const int quad = lane >> 4;
    const int koff = quad * 8;

    // B fragments: 64 cols x K=128 -> 64 VGPRs
    short8 Bf[4][4];
    #pragma unroll
    for (int j = 0; j < 4; j++)
        #pragma unroll
        for (int ks = 0; ks < 4; ks++)
            Bf[j][ks] = *(const short8*)(wsw + (size_t)(h * 64 + j * 16 + l15) * E_ + ks * 32 + koff);

    const int* xrow = x + b * T_ + tbase;
    const float* srow = scores + b * T_ + tbase;

    float mm[4] = { -INFINITY, -INFINITY, -INFINITY, -INFINITY };

    // ---- pipeline preheader: chunk 0 ----
    int idx_n = xrow[l15];                       // chunk 0 row index
    short8 Acur[4];
    {
        const short* rp = tab + (size_t)idx_n * E_ + koff;
        Acur[0] = *(const short8*)(rp);
        Acur[1] = *(const short8*)(rp + 32);
        Acur[2] = *(const short8*)(rp + 64);
        Acur[3] = *(const short8*)(rp + 96);
    }
    float4 sc_cur = *(const float4*)(srow + quad * 4);
    idx_n = xrow[16 + l15];                      // chunk 1 row index

    #pragma unroll
    for (int cch = 0; cch < MCH; cch++) {
        short8 Anx[4];
        float4 sc_nx;
        // issue next chunk's A / score loads early; they fly under the MFMAs
        if (cch + 1 < MCH) {
            const short* rp = tab + (size_t)idx_n * E_ + koff;
            Anx[0] = *(const short8*)(rp);
            Anx[1] = *(const short8*)(rp + 32);
            Anx[2] = *(const short8*)(rp + 64);
            Anx[3] = *(const short8*)(rp + 96);
            sc_nx = *(const float4*)(srow + (cch + 1) * 16 + quad * 4);
            if (cch + 2 < MCH) idx_n = xrow[(cch + 2) * 16 + l15];
        }

        floatx4 acc[4];
        #pragma unroll
        for (int j = 0; j < 4; j++) acc[j] = (floatx4){0.f, 0.f, 0.f, 0.f};
        #pragma unroll
        for (int ks = 0; ks < 4; ks++)
            #pragma unroll
            for (int j = 0; j < 4; j++)
                acc[j] = __builtin_amdgcn_mfma_f32_16x16x32_bf16(Acur[ks], Bf[j][ks], acc[j], 0, 0, 0);

        float scr[4] = { sc_cur.x, sc_cur.y, sc_cur.z, sc_cur.w };
        #pragma unroll
        for (int j = 0; j < 4; j++)
            #pragma unroll
            for (int r = 0; r < 4; r++)
                mm[j] = fmaxf(mm[j], scr[r] * acc[j][r]);

        if (cch + 1 < MCH) {
            #pragma unroll
            for (int k = 0; k < 4; k++) Acur[k] = Anx[k];
            sc_cur = sc_nx;
        }
    }

    // ---- reduce over quads, tanh(+bias), atomicMax ----
    #pragma unroll
    for (int j = 0; j < 4; j++) {
        float m = mm[j];
        m = fmaxf(m, __shfl_xor(m, 16));
        m = fmaxf(m, __shfl_xor(m, 32));
        if (lane < 16) {
            int o = h * 64 + j * 16 + lane;
            atomicMaxFloat(&out[b * OC_ + o], tanhf(m + cnn_b[o]));
        }
    }
}

// ============ fallback (small ws): monolithic fp32-gather version ============
__global__ void prep_small(const float* __restrict__ cnn_w, const float* __restrict__ att_w,
                           short* __restrict__ wsw, short* __restrict__ wsatt) {
    int i = blockIdx.x * 256 + threadIdx.x;
    if (i < OC_ * E_)  wsw[i]   = f2bf(cnn_w[i]);
    if (i < WIN_ * E_) wsatt[i] = f2bf(att_w[i]);
}

__launch_bounds__(256, 4)
__global__ void fallback_main(const int* __restrict__ x,
                              const float* __restrict__ emb,
                              const float* __restrict__ att_b_p,
                              const short* __restrict__ wsw,
                              const short* __restrict__ wsatt,
                              const float* __restrict__ cnn_b,
                              float* __restrict__ out) {
    __shared__ short sh_a[ROWS * ASTR];
    __shared__ short sh_att[16 * ASTR];
    __shared__ float sh_r[ROWS * 8];
    __shared__ float sh_score[TT];
    __shared__ int   sh_idx[8 * ROWS];

    const int tid  = threadIdx.x;
    const int lane = tid & 63;
    const int w    = tid >> 6;
    const int b    = blockIdx.y;
    const int t0   = blockIdx.x * (8 * TT);
    const int l15  = lane & 15;
    const int quad = lane >> 4;
    const int rbase = tid >> 4;
    const int c     = tid & 15;

    for (int i = tid; i < 8 * ROWS; i += 256) {
        int tile = i / ROWS, row = i - tile * ROWS;
        int t = t0 + tile * TT + row - PAD_;
        sh_idx[i] = (row < REAL_ROWS && t >= 0 && t < T_) ? x[b * T_ + t] : -1;
    }
    {
        int o = tid >> 4, cc = tid & 15;
        short8 v = (short8){0,0,0,0,0,0,0,0};
        if (o < WIN_) v = *(const short8*)(wsatt + o * E_ + cc * 8);
        *(short8*)(&sh_att[o * ASTR + cc * 8]) = v;
    }
    short8 Bf[2][4];
    #pragma unroll
    for (int j = 0; j < 2; j++)
        #pragma unroll
        for (int ks = 0; ks < 4; ks++)
            Bf[j][ks] = *(const short8*)(wsw + (size_t)(w * 32 + j * 16 + l15) * E_ + ks * 32 + quad * 8);
    __syncthreads();

    short8 g[5];
    #pragma unroll
    for (int k = 0; k < 5; k++) {
        int idx = sh_idx[rbase + 16 * k];
        short8 v = (short8){0,0,0,0,0,0,0,0};
        if (idx >= 0) {
            const float4* p = (const float4*)(emb + (size_t)idx * E_ + c * 8);
            float4 p0 = p[0], p1 = p[1];
            v = (short8){ f2bf(p0.x), f2bf(p0.y), f2bf(p0.z), f2bf(p0.w),
                          f2bf(p1.x), f2bf(p1.y), f2bf(p1.z), f2bf(p1.w) };
        }
        g[k] = v;
    }
    #pragma unroll
    for (int k = 0; k < 5; k++)
        *(short8*)(&sh_a[(rbase + 16 * k) * ASTR + c * 8]) = g[k];
    __syncthreads();

    const float attb = att_b_p[0];
    float mm[2] = { -INFINITY, -INFINITY };

    for (int it = 0; it < 8; it++) {
        for (int mt = w; mt < 5; mt += 4) {
            floatx4 acc = (floatx4){0.f, 0.f, 0.f, 0.f};
            #pragma unroll
            for (int ks = 0; ks < 4; ks++) {
                short8 a  = *(const short8*)(&sh_a[(mt * 16 + l15) * ASTR + ks * 32 + quad * 8]);
                short8 bs = *(const short8*)(&sh_att[l15 * ASTR + ks * 32 + quad * 8]);
                acc = __builtin_amdgcn_mfma_f32_16x16x32_bf16(a, bs, acc, 0, 0, 0);
            }
            if (l15 < 8) {
                #pragma unroll
                for (int r = 0; r < 4; r++)
                    sh_r[(mt * 16 + quad * 4 + r) * 8 + l15] = acc[r];
            }
        }
        __syncthreads();

        if (it + 1 < 8) {
            const int* idxp = &sh_idx[(it + 1) * ROWS];
            #pragma unroll
            for (int k = 0; k < 5; k++) {
                int idx = idxp[rbase + 16 * k];
                short8 v = (short8){0,0,0,0,0,0,0,0};
                if (idx >= 0) {
                    const float4* p = (const float4*)(emb + (size_t)idx * E_ + c * 8);
                    float4 p0 = p[0], p1 = p[1];
                    v = (short8){ f2bf(p0.x), f2bf(p0.y), f2bf(p0.z), f2bf(p0.w),
                                  f2bf(p1.x), f2bf(p1.y), f2bf(p1.z), f2bf(p1.w) };
                }
                g[k] = v;
            }
        }

        if (tid < TT) {
            float s = attb;
            #pragma unroll
            for (int k = 0; k < WIN_; k++) s += sh_r[(tid + k) * 8 + k];
            sh_score[tid] = 1.0f / (1.0f + __expf(-s));
        }

        floatx4 acc[4][2];
        #pragma unroll
        for (int i = 0; i < 4; i++)
            #pragma unroll
            for (int j = 0; j < 2; j++) acc[i][j] = (floatx4){0.f, 0.f, 0.f, 0.f};
        #pragma unroll
        for (int ks = 0; ks < 4; ks++) {
            int ko = ks * 32 + quad * 8;
            #pragma unroll
            for (int i = 0; i < 4; i++) {
                short8 ai = *(const short8*)(&sh_a[(PAD_ + i * 16 + l15) * ASTR + ko]);
                acc[i][0] = __builtin_amdgcn_mfma_f32_16x16x32_bf16(ai, Bf[0][ks], acc[i][0], 0, 0, 0);
                acc[i][1] = __builtin_amdgcn_mfma_f32_16x16x32_bf16(ai, Bf[1][ks], acc[i][1], 0, 0, 0);
            }
        }
        __syncthreads();

        #pragma unroll
        for (int i = 0; i < 4; i++) {
            #pragma unroll
            for (int r = 0; r < 4; r++) {
                float sc = sh_score[i * 16 + quad * 4 + r];
                mm[0] = fmaxf(mm[0], sc * acc[i][0][r]);
                mm[1] = fmaxf(mm[1], sc * acc[i][1][r]);
            }
        }

        if (it + 1 < 8) {
            #pragma unroll
            for (int k = 0; k < 5; k++)
                *(short8*)(&sh_a[(rbase + 16 * k) * ASTR + c * 8]) = g[k];
            __syncthreads();
        }
    }

    #pragma unroll
    for (int j = 0; j < 2; j++) {
        float m = mm[j];
        m = fmaxf(m, __shfl_xor(m, 16));
        m = fmaxf(m, __shfl_xor(m, 32));
        if (lane < 16) {
            int o = w * 32 + j * 16 + lane;
            atomicMaxFloat(&out[b * OC_ + o], tanhf(m + cnn_b[o]));
        }
    }
}

extern "C" void kernel_launch(void* const* d_in, const int* in_sizes, int n_in,
                              void* d_out, int out_size, void* d_ws, size_t ws_size,
                              hipStream_t stream) {
    const int*   x     = (const int*)d_in[0];
    const float* emb   = (const float*)d_in[1];
    const float* att_w = (const float*)d_in[2];
    const float* att_b = (const float*)d_in[3];
    const float* cnn_w = (const float*)d_in[4];
    const float* cnn_b = (const float*)d_in[5];
    float* out = (float*)d_out;

    hipMemsetAsync(d_out, 0xFF, (size_t)B_ * OC_ * sizeof(float), stream);

    const size_t tab_elems = (size_t)VOCAB1 * E_;                 // bf16 count
    const size_t need = tab_elems * 2 + OC_ * E_ * 2 + WIN_ * E_ * 2
                      + (size_t)B_ * T_ * 4 + 64;

    if (ws_size >= need) {
        short* tab    = (short*)d_ws;
        short* ws_w   = tab + tab_elems;
        short* ws_att = ws_w + OC_ * E_;
        float* scores = (float*)(ws_att + WIN_ * E_);
        long total = (NTAB_CH + OC_ * E_ / 8 + WIN_ * E_ / 8 + 1) / 2;
        prep_full<<<(int)((total + 255) / 256), 256, 0, stream>>>(emb, cnn_w, att_w, tab, ws_w, ws_att);
        dim3 sgrid(T_ / TT, B_);            // (32, 256)
        score_kernel<<<sgrid, 256, 0, stream>>>(x, tab, att_b, ws_att, scores);
        dim3 mgrid(T_ / 256, B_);           // (8, 256)
        gemm_max<<<mgrid, 256, 0, stream>>>(x, tab, scores, ws_w, cnn_b, out);
    } else {
        short* ws_w   = (short*)d_ws;
        short* ws_att = ws_w + OC_ * E_;
        prep_small<<<16, 256, 0, stream>>>(cnn_w, att_w, ws_w, ws_att);
        dim3 grid(T_ / (8 * TT), B_);
        fallback_main<<<grid, 256, 0, stream>>>(x, emb, att_b, ws_w, ws_att, cnn_b, out);
    }
}

// Round 7
// 131.152 us; speedup vs baseline: 1.6125x; 1.6125x over previous
//
#include <hip/hip_runtime.h>
#include <hip/hip_bf16.h>
#include <math.h>

// B,T,E,WIN,OC,VOCAB = 256,2048,128,5,128,50000
#define B_   256
#define T_   2048
#define E_   128
#define WIN_ 5
#define PAD_ 2
#define OC_  128
#define VOCAB1 50001
#define TT   64                   // tokens per tile
#define REAL_ROWS (TT + WIN_ - 1) // 68 rows incl. halo (score kernel)
#define ROWS 80                   // padded to 5 m-tiles of 16 (score kernel)
#define ASTR 136                  // LDS row stride (bf16): 272B -> 2-way alias = free
#define MNT  8                    // tiles per block in gemm kernel (512 tokens)

#define NTAB_CH (VOCAB1 * E_ / 8) // 800016 short8 chunks

typedef __attribute__((ext_vector_type(8))) short short8;
typedef __attribute__((ext_vector_type(4))) float floatx4;

static __device__ __forceinline__ short f2bf(float f) {
    union { __hip_bfloat16 h; short s; } u;
    u.h = __float2bfloat16(f);
    return u.s;
}

__device__ __forceinline__ void atomicMaxFloat(float* addr, float v) {
    // works with 0xFFFFFFFF init pattern on both paths
    if (v >= 0.0f) atomicMax((int*)addr, __float_as_int(v));
    else           atomicMin((unsigned int*)addr, __float_as_uint(v));
}

__device__ __forceinline__ void conv_chunk(long i, const float* __restrict__ emb,
                                           const float* __restrict__ cnn_w,
                                           const float* __restrict__ att_w,
                                           short* __restrict__ tab, short* __restrict__ wsw,
                                           short* __restrict__ wsatt) {
    const float* src;
    short* dst;
    if (i < NTAB_CH) { src = emb; dst = tab; }
    else if ((i -= NTAB_CH) < OC_ * E_ / 8) { src = cnn_w; dst = wsw; }
    else if ((i -= OC_ * E_ / 8) < WIN_ * E_ / 8) { src = att_w; dst = wsatt; }
    else return;
    const float4* s = (const float4*)src + (size_t)i * 2;
    float4 a = s[0], b = s[1];
    short8 o = { f2bf(a.x), f2bf(a.y), f2bf(a.z), f2bf(a.w),
                 f2bf(b.x), f2bf(b.y), f2bf(b.z), f2bf(b.w) };
    *(short8*)(dst + (size_t)i * 8) = o;
}

// ---- prep: bf16 table + cnn_w + att_w into ws (2 chunks/thread) ----
__global__ void prep_full(const float* __restrict__ emb, const float* __restrict__ cnn_w,
                          const float* __restrict__ att_w,
                          short* __restrict__ tab, short* __restrict__ wsw,
                          short* __restrict__ wsatt) {
    long i = (long)(blockIdx.x * 256 + threadIdx.x) * 2;
    conv_chunk(i,     emb, cnn_w, att_w, tab, wsw, wsatt);
    conv_chunk(i + 1, emb, cnn_w, att_w, tab, wsw, wsatt);
}

// =====================  Kernel S: scores[B,T]  =====================
__launch_bounds__(256, 4)
__global__ void score_kernel(const int* __restrict__ x,
                             const short* __restrict__ tab,
                             const float* __restrict__ att_b_p,
                             const short* __restrict__ wsatt,
                             float* __restrict__ scores) {
    __shared__ short sh_a[ROWS * ASTR];     // 21760 B
    __shared__ short sh_att[16 * ASTR];     // 4352 B
    __shared__ float sh_r[ROWS * 8];        // 2560 B
    __shared__ int   sh_idx[ROWS];

    const int tid  = threadIdx.x;
    const int lane = tid & 63;
    const int w    = tid >> 6;
    const int b    = blockIdx.y;
    const int t0   = blockIdx.x * TT;
    const int l15  = lane & 15;
    const int quad = lane >> 4;
    const int rbase = tid >> 4;
    const int c     = tid & 15;

    if (tid < ROWS) {
        int gt = t0 + tid - PAD_;
        sh_idx[tid] = (tid < REAL_ROWS && gt >= 0 && gt < T_) ? x[b * T_ + gt] : -1;
    }
    {
        int o = tid >> 4, cc = tid & 15;
        short8 v = (short8){0,0,0,0,0,0,0,0};
        if (o < WIN_) v = *(const short8*)(wsatt + o * E_ + cc * 8);
        *(short8*)(&sh_att[o * ASTR + cc * 8]) = v;
    }
    __syncthreads();

    #pragma unroll
    for (int k = 0; k < 5; k++) {
        int row = rbase + 16 * k;
        int idx = sh_idx[row];
        short8 v = (short8){0,0,0,0,0,0,0,0};
        if (idx >= 0) v = *(const short8*)(tab + (size_t)idx * E_ + c * 8);
        *(short8*)(&sh_a[row * ASTR + c * 8]) = v;
    }
    __syncthreads();

    for (int mt = w; mt < 5; mt += 4) {
        floatx4 acc = (floatx4){0.f, 0.f, 0.f, 0.f};
        #pragma unroll
        for (int ks = 0; ks < 4; ks++) {
            short8 a  = *(const short8*)(&sh_a[(mt * 16 + l15) * ASTR + ks * 32 + quad * 8]);
            short8 bs = *(const short8*)(&sh_att[l15 * ASTR + ks * 32 + quad * 8]);
            acc = __builtin_amdgcn_mfma_f32_16x16x32_bf16(a, bs, acc, 0, 0, 0);
        }
        if (l15 < 8) {
            #pragma unroll
            for (int r = 0; r < 4; r++)
                sh_r[(mt * 16 + quad * 4 + r) * 8 + l15] = acc[r];
        }
    }
    __syncthreads();

    if (tid < TT) {
        float s = att_b_p[0];
        #pragma unroll
        for (int k = 0; k < WIN_; k++) s += sh_r[(tid + k) * 8 + k];
        scores[b * T_ + t0 + tid] = 1.0f / (1.0f + __expf(-s));
    }
}

// ============  Kernel M: LDS-staged GEMM+max, 1 barrier/tile  ============
// Wave w owns cols [w*32, w*32+32). Block processes MNT tiles of 64 tokens,
// A double-buffered in LDS. Scores precomputed by kernel S.
__launch_bounds__(256, 4)
__global__ void gemm_max(const int* __restrict__ x,
                         const short* __restrict__ tab,
                         const float* __restrict__ scores,
                         const short* __restrict__ wsw,
                         const float* __restrict__ cnn_b,
                         float* __restrict__ out) {
    __shared__ short sh_a[2][TT * ASTR];    // 2 x 17408 B
    __shared__ int   sh_idx[MNT * TT];      // 2048 B -> 36.9 KB total

    const int tid  = threadIdx.x;
    const int lane = tid & 63;
    const int w    = tid >> 6;
    const int b    = blockIdx.y;
    const int t0   = blockIdx.x * (MNT * TT);
    const int l15  = lane & 15;
    const int quad = lane >> 4;
    const int rbase = tid >> 4;             // staging: rows rbase+16k (k<4), chunk c
    const int c     = tid & 15;

    // ---- stage all 512 token indices (coalesced) ----
    sh_idx[tid]       = x[b * T_ + t0 + tid];
    sh_idx[tid + 256] = x[b * T_ + t0 + tid + 256];

    // ---- B fragments: 32 cols/wave ----
    short8 Bf[2][4];
    #pragma unroll
    for (int j = 0; j < 2; j++)
        #pragma unroll
        for (int ks = 0; ks < 4; ks++)
            Bf[j][ks] = *(const short8*)(wsw + (size_t)(w * 32 + j * 16 + l15) * E_ + ks * 32 + quad * 8);
    __syncthreads();                        // sh_idx ready

    // ---- stage tile 0 ----
    short8 g[4];
    #pragma unroll
    for (int k = 0; k < 4; k++) {
        int idx = sh_idx[rbase + 16 * k];
        g[k] = *(const short8*)(tab + (size_t)idx * E_ + c * 8);
    }
    #pragma unroll
    for (int k = 0; k < 4; k++)
        *(short8*)(&sh_a[0][(rbase + 16 * k) * ASTR + c * 8]) = g[k];
    __syncthreads();                        // buf 0 ready

    const float* srow = scores + b * T_ + t0;
    float mm[2] = { -INFINITY, -INFINITY };

    for (int it = 0; it < MNT; it++) {
        const int cur = it & 1;
        const short* A = &sh_a[cur][0];

        // 1) issue next tile's gathers — they fly under the 32 MFMAs below
        if (it + 1 < MNT) {
            const int* idxp = &sh_idx[(it + 1) * TT];
            #pragma unroll
            for (int k = 0; k < 4; k++) {
                int idx = idxp[rbase + 16 * k];
                g[k] = *(const short8*)(tab + (size_t)idx * E_ + c * 8);
            }
        }

        // 2) compute: 4 m-tiles x (2 cols-tiles x 4 ks) on current buffer
        #pragma unroll
        for (int i = 0; i < 4; i++) {
            float4 sc = *(const float4*)(srow + it * TT + i * 16 + quad * 4);
            short8 a0 = *(const short8*)(&A[(i * 16 + l15) * ASTR +  0 + quad * 8]);
            short8 a1 = *(const short8*)(&A[(i * 16 + l15) * ASTR + 32 + quad * 8]);
            short8 a2 = *(const short8*)(&A[(i * 16 + l15) * ASTR + 64 + quad * 8]);
            short8 a3 = *(const short8*)(&A[(i * 16 + l15) * ASTR + 96 + quad * 8]);
            floatx4 acc0 = (floatx4){0.f, 0.f, 0.f, 0.f};
            floatx4 acc1 = (floatx4){0.f, 0.f, 0.f, 0.f};
            acc0 = __builtin_amdgcn_mfma_f32_16x16x32_bf16(a0, Bf[0][0], acc0, 0, 0, 0);
            acc1 = __builtin_amdgcn_mfma_f32_16x16x32_bf16(a0, Bf[1][0], acc1, 0, 0, 0);
            acc0 = __builtin_amdgcn_mfma_f32_16x16x32_bf16(a1, Bf[0][1], acc0, 0, 0, 0);
            acc1 = __builtin_amdgcn_mfma_f32_16x16x32_bf16(a1, Bf[1][1], acc1, 0, 0, 0);
            acc0 = __builtin_amdgcn_mfma_f32_16x16x32_bf16(a2, Bf[0][2], acc0, 0, 0, 0);
            acc1 = __builtin_amdgcn_mfma_f32_16x16x32_bf16(a2, Bf[1][2], acc1, 0, 0, 0);
            acc0 = __builtin_amdgcn_mfma_f32_16x16x32_bf16(a3, Bf[0][3], acc0, 0, 0, 0);
            acc1 = __builtin_amdgcn_mfma_f32_16x16x32_bf16(a3, Bf[1][3], acc1, 0, 0, 0);
            float scr[4] = { sc.x, sc.y, sc.z, sc.w };
            #pragma unroll
            for (int r = 0; r < 4; r++) {
                mm[0] = fmaxf(mm[0], scr[r] * acc0[r]);
                mm[1] = fmaxf(mm[1], scr[r] * acc1[r]);
            }
        }

        // 3) commit next tile into the other buffer, single barrier
        if (it + 1 < MNT) {
            #pragma unroll
            for (int k = 0; k < 4; k++)
                *(short8*)(&sh_a[cur ^ 1][(rbase + 16 * k) * ASTR + c * 8]) = g[k];
            __syncthreads();
        }
    }

    // ---- reduce over quads, tanh(+bias), atomicMax ----
    #pragma unroll
    for (int j = 0; j < 2; j++) {
        float m = mm[j];
        m = fmaxf(m, __shfl_xor(m, 16));
        m = fmaxf(m, __shfl_xor(m, 32));
        if (lane < 16) {
            int o = w * 32 + j * 16 + lane;
            atomicMaxFloat(&out[b * OC_ + o], tanhf(m + cnn_b[o]));
        }
    }
}

// ============ fallback (small ws): monolithic fp32-gather version ============
__global__ void prep_small(const float* __restrict__ cnn_w, const float* __restrict__ att_w,
                           short* __restrict__ wsw, short* __restrict__ wsatt) {
    int i = blockIdx.x * 256 + threadIdx.x;
    if (i < OC_ * E_)  wsw[i]   = f2bf(cnn_w[i]);
    if (i < WIN_ * E_) wsatt[i] = f2bf(att_w[i]);
}

__launch_bounds__(256, 4)
__global__ void fallback_main(const int* __restrict__ x,
                              const float* __restrict__ emb,
                              const float* __restrict__ att_b_p,
                              const short* __restrict__ wsw,
                              const short* __restrict__ wsatt,
                              const float* __restrict__ cnn_b,
                              float* __restrict__ out) {
    __shared__ short sh_a[ROWS * ASTR];
    __shared__ short sh_att[16 * ASTR];
    __shared__ float sh_r[ROWS * 8];
    __shared__ float sh_score[TT];
    __shared__ int   sh_idx[8 * ROWS];

    const int tid  = threadIdx.x;
    const int lane = tid & 63;
    const int w    = tid >> 6;
    const int b    = blockIdx.y;
    const int t0   = blockIdx.x * (8 * TT);
    const int l15  = lane & 15;
    const int quad = lane >> 4;
    const int rbase = tid >> 4;
    const int c     = tid & 15;

    for (int i = tid; i < 8 * ROWS; i += 256) {
        int tile = i / ROWS, row = i - tile * ROWS;
        int t = t0 + tile * TT + row - PAD_;
        sh_idx[i] = (row < REAL_ROWS && t >= 0 && t < T_) ? x[b * T_ + t] : -1;
    }
    {
        int o = tid >> 4, cc = tid & 15;
        short8 v = (short8){0,0,0,0,0,0,0,0};
        if (o < WIN_) v = *(const short8*)(wsatt + o * E_ + cc * 8);
        *(short8*)(&sh_att[o * ASTR + cc * 8]) = v;
    }
    short8 Bf[2][4];
    #pragma unroll
    for (int j = 0; j < 2; j++)
        #pragma unroll
        for (int ks = 0; ks < 4; ks++)
            Bf[j][ks] = *(const short8*)(wsw + (size_t)(w * 32 + j * 16 + l15) * E_ + ks * 32 + quad * 8);
    __syncthreads();

    short8 g[5];
    #pragma unroll
    for (int k = 0; k < 5; k++) {
        int idx = sh_idx[rbase + 16 * k];
        short8 v = (short8){0,0,0,0,0,0,0,0};
        if (idx >= 0) {
            const float4* p = (const float4*)(emb + (size_t)idx * E_ + c * 8);
            float4 p0 = p[0], p1 = p[1];
            v = (short8){ f2bf(p0.x), f2bf(p0.y), f2bf(p0.z), f2bf(p0.w),
                          f2bf(p1.x), f2bf(p1.y), f2bf(p1.z), f2bf(p1.w) };
        }
        g[k] = v;
    }
    #pragma unroll
    for (int k = 0; k < 5; k++)
        *(short8*)(&sh_a[(rbase + 16 * k) * ASTR + c * 8]) = g[k];
    __syncthreads();

    const float attb = att_b_p[0];
    float mm[2] = { -INFINITY, -INFINITY };

    for (int it = 0; it < 8; it++) {
        for (int mt = w; mt < 5; mt += 4) {
            floatx4 acc = (floatx4){0.f, 0.f, 0.f, 0.f};
            #pragma unroll
            for (int ks = 0; ks < 4; ks++) {
                short8 a  = *(const short8*)(&sh_a[(mt * 16 + l15) * ASTR + ks * 32 + quad * 8]);
                short8 bs = *(const short8*)(&sh_att[l15 * ASTR + ks * 32 + quad * 8]);
                acc = __builtin_amdgcn_mfma_f32_16x16x32_bf16(a, bs, acc, 0, 0, 0);
            }
            if (l15 < 8) {
                #pragma unroll
                for (int r = 0; r < 4; r++)
                    sh_r[(mt * 16 + quad * 4 + r) * 8 + l15] = acc[r];
            }
        }
        __syncthreads();

        if (it + 1 < 8) {
            const int* idxp = &sh_idx[(it + 1) * ROWS];
            #pragma unroll
            for (int k = 0; k < 5; k++) {
                int idx = idxp[rbase + 16 * k];
                short8 v = (short8){0,0,0,0,0,0,0,0};
                if (idx >= 0) {
                    const float4* p = (const float4*)(emb + (size_t)idx * E_ + c * 8);
                    float4 p0 = p[0], p1 = p[1];
                    v = (short8){ f2bf(p0.x), f2bf(p0.y), f2bf(p0.z), f2bf(p0.w),
                                  f2bf(p1.x), f2bf(p1.y), f2bf(p1.z), f2bf(p1.w) };
                }
                g[k] = v;
            }
        }

        if (tid < TT) {
            float s = attb;
            #pragma unroll
            for (int k = 0; k < WIN_; k++) s += sh_r[(tid + k) * 8 + k];
            sh_score[tid] = 1.0f / (1.0f + __expf(-s));
        }

        floatx4 acc[4][2];
        #pragma unroll
        for (int i = 0; i < 4; i++)
            #pragma unroll
            for (int j = 0; j < 2; j++) acc[i][j] = (floatx4){0.f, 0.f, 0.f, 0.f};
        #pragma unroll
        for (int ks = 0; ks < 4; ks++) {
            int ko = ks * 32 + quad * 8;
            #pragma unroll
            for (int i = 0; i < 4; i++) {
                short8 ai = *(const short8*)(&sh_a[(PAD_ + i * 16 + l15) * ASTR + ko]);
                acc[i][0] = __builtin_amdgcn_mfma_f32_16x16x32_bf16(ai, Bf[0][ks], acc[i][0], 0, 0, 0);
                acc[i][1] = __builtin_amdgcn_mfma_f32_16x16x32_bf16(ai, Bf[1][ks], acc[i][1], 0, 0, 0);
            }
        }
        __syncthreads();

        #pragma unroll
        for (int i = 0; i < 4; i++) {
            #pragma unroll
            for (int r = 0; r < 4; r++) {
                float sc = sh_score[i * 16 + quad * 4 + r];
                mm[0] = fmaxf(mm[0], sc * acc[i][0][r]);
                mm[1] = fmaxf(mm[1], sc * acc[i][1][r]);
            }
        }

        if (it + 1 < 8) {
            #pragma unroll
            for (int k = 0; k < 5; k++)
                *(short8*)(&sh_a[(rbase + 16 * k) * ASTR + c * 8]) = g[k];
            __syncthreads();
        }
    }

    #pragma unroll
    for (int j = 0; j < 2; j++) {
        float m = mm[j];
        m = fmaxf(m, __shfl_xor(m, 16));
        m = fmaxf(m, __shfl_xor(m, 32));
        if (lane < 16) {
            int o = w * 32 + j * 16 + lane;
            atomicMaxFloat(&out[b * OC_ + o], tanhf(m + cnn_b[o]));
        }
    }
}

extern "C" void kernel_launch(void* const* d_in, const int* in_sizes, int n_in,
                              void* d_out, int out_size, void* d_ws, size_t ws_size,
                              hipStream_t stream) {
    const int*   x     = (const int*)d_in[0];
    const float* emb   = (const float*)d_in[1];
    const float* att_w = (const float*)d_in[2];
    const float* att_b = (const float*)d_in[3];
    const float* cnn_w = (const float*)d_in[4];
    const float* cnn_b = (const float*)d_in[5];
    float* out = (float*)d_out;

    hipMemsetAsync(d_out, 0xFF, (size_t)B_ * OC_ * sizeof(float), stream);

    const size_t tab_elems = (size_t)VOCAB1 * E_;                 // bf16 count
    const size_t need = tab_elems * 2 + OC_ * E_ * 2 + WIN_ * E_ * 2
                      + (size_t)B_ * T_ * 4 + 64;

    if (ws_size >= need) {
        short* tab    = (short*)d_ws;
        short* ws_w   = tab + tab_elems;
        short* ws_att = ws_w + OC_ * E_;
        float* scores = (float*)(ws_att + WIN_ * E_);
        long total = (NTAB_CH + OC_ * E_ / 8 + WIN_ * E_ / 8 + 1) / 2;
        prep_full<<<(int)((total + 255) / 256), 256, 0, stream>>>(emb, cnn_w, att_w, tab, ws_w, ws_att);
        dim3 sgrid(T_ / TT, B_);            // (32, 256)
        score_kernel<<<sgrid, 256, 0, stream>>>(x, tab, att_b, ws_att, scores);
        dim3 mgrid(T_ / (MNT * TT), B_);    // (4, 256) = 1024 blocks
        gemm_max<<<mgrid, 256, 0, stream>>>(x, tab, scores, ws_w, cnn_b, out);
    } else {
        short* ws_w   = (short*)d_ws;
        short* ws_att = ws_w + OC_ * E_;
        prep_small<<<16, 256, 0, stream>>>(cnn_w, att_w, ws_w, ws_att);
        dim3 grid(T_ / (8 * TT), B_);
        fallback_main<<<grid, 256, 0, stream>>>(x, emb, att_b, ws_w, ws_att, cnn_b, out);
    }
}

// Round 8
// 119.108 us; speedup vs baseline: 1.7756x; 1.1011x over previous
//
#include <hip/hip_runtime.h>
#include <hip/hip_bf16.h>
#include <math.h>

// B,T,E,WIN,OC,VOCAB = 256,2048,128,5,128,50000
#define B_   256
#define T_   2048
#define E_   128
#define WIN_ 5
#define PAD_ 2
#define OC_  128
#define VOCAB_MAX 50000
#define VOCAB1 50001
#define TT   64
#define REAL_ROWS (TT + WIN_ - 1)
#define ROWS 80
#define ASTR 136                  // LDS row stride (bf16): 272B -> 2-way alias = free
#define VROWS 64                  // vocab rows per build_tables block

typedef __attribute__((ext_vector_type(8))) short short8;
typedef __attribute__((ext_vector_type(4))) float floatx4;

static __device__ __forceinline__ short f2bf(float f) {
    union { __hip_bfloat16 h; short s; } u;
    u.h = __float2bfloat16(f);
    return u.s;
}

__device__ __forceinline__ void atomicMaxFloat(float* addr, float v) {
    // works with 0xFFFFFFFF init pattern on both paths
    if (v >= 0.0f) atomicMax((int*)addr, __float_as_int(v));
    else           atomicMin((unsigned int*)addr, __float_as_uint(v));
}

// ============ P1: vocab-level tables ============
// D[v][o] = <emb[v], cnn_w[o]>  (bf16)
// r[v][k] = <emb[v], att_w[k]>  (fp32, k<5; slots 5..7 zero)
__launch_bounds__(256, 2)
__global__ void build_tables(const float* __restrict__ emb,
                             const float* __restrict__ cnn_w,
                             const float* __restrict__ att_w,
                             short* __restrict__ D,
                             float* __restrict__ r) {
    __shared__ short sh_a[VROWS * ASTR];   // 17408 B

    const int tid  = threadIdx.x;
    const int lane = tid & 63;
    const int w    = tid >> 6;
    const int l15  = lane & 15;
    const int quad = lane >> 4;
    const int v0   = blockIdx.x * VROWS;

    // stage 64 vocab rows fp32 -> bf16 (fully coalesced; clamp OOB rows)
    #pragma unroll
    for (int t = 0; t < 8; t++) {
        int i   = t * 256 + tid;          // 2048 float4 chunks
        int row = i >> 5, c4 = i & 31;
        int vr  = v0 + row; if (vr > VOCAB_MAX) vr = VOCAB_MAX;
        float4 v = *(const float4*)(emb + (size_t)vr * E_ + c4 * 4);
        short4 o; o.x = f2bf(v.x); o.y = f2bf(v.y); o.z = f2bf(v.z); o.w = f2bf(v.w);
        *(short4*)(&sh_a[row * ASTR + c4 * 4]) = o;
    }

    // B fragments (cnn_w fp32 -> bf16): wave w -> cols [w*32, w*32+32)
    short8 Bf[2][4];
    #pragma unroll
    for (int j = 0; j < 2; j++)
        #pragma unroll
        for (int ks = 0; ks < 4; ks++) {
            const float4* p = (const float4*)(cnn_w + (size_t)(w * 32 + j * 16 + l15) * E_ + ks * 32 + quad * 8);
            float4 p0 = p[0], p1 = p[1];
            Bf[j][ks] = (short8){ f2bf(p0.x), f2bf(p0.y), f2bf(p0.z), f2bf(p0.w),
                                  f2bf(p1.x), f2bf(p1.y), f2bf(p1.z), f2bf(p1.w) };
        }

    // att-tap fragments (taps >= WIN_ are zero)
    short8 Ba[4];
    #pragma unroll
    for (int ks = 0; ks < 4; ks++) {
        short8 v = (short8){0,0,0,0,0,0,0,0};
        if (l15 < WIN_) {
            const float4* p = (const float4*)(att_w + (size_t)l15 * E_ + ks * 32 + quad * 8);
            float4 p0 = p[0], p1 = p[1];
            v = (short8){ f2bf(p0.x), f2bf(p0.y), f2bf(p0.z), f2bf(p0.w),
                          f2bf(p1.x), f2bf(p1.y), f2bf(p1.z), f2bf(p1.w) };
        }
        Ba[ks] = v;
    }
    __syncthreads();

    // D tiles: 4 m-tiles x 2 n-tiles per wave
    #pragma unroll
    for (int mt = 0; mt < 4; mt++) {
        short8 a[4];
        #pragma unroll
        for (int ks = 0; ks < 4; ks++)
            a[ks] = *(const short8*)(&sh_a[(mt * 16 + l15) * ASTR + ks * 32 + quad * 8]);
        #pragma unroll
        for (int j = 0; j < 2; j++) {
            floatx4 acc = (floatx4){0.f, 0.f, 0.f, 0.f};
            #pragma unroll
            for (int ks = 0; ks < 4; ks++)
                acc = __builtin_amdgcn_mfma_f32_16x16x32_bf16(a[ks], Bf[j][ks], acc, 0, 0, 0);
            #pragma unroll
            for (int rr = 0; rr < 4; rr++) {
                int v = v0 + mt * 16 + quad * 4 + rr;
                if (v <= VOCAB_MAX)
                    D[(size_t)v * E_ + w * 32 + j * 16 + l15] = f2bf(acc[rr]);
            }
        }
    }

    // r tile: wave w handles m-tile w
    {
        short8 a[4];
        #pragma unroll
        for (int ks = 0; ks < 4; ks++)
            a[ks] = *(const short8*)(&sh_a[(w * 16 + l15) * ASTR + ks * 32 + quad * 8]);
        floatx4 acc = (floatx4){0.f, 0.f, 0.f, 0.f};
        #pragma unroll
        for (int ks = 0; ks < 4; ks++)
            acc = __builtin_amdgcn_mfma_f32_16x16x32_bf16(a[ks], Ba[ks], acc, 0, 0, 0);
        if (l15 < 8) {
            #pragma unroll
            for (int rr = 0; rr < 4; rr++) {
                int v = v0 + w * 16 + quad * 4 + rr;
                if (v <= VOCAB_MAX) r[(size_t)v * 8 + l15] = acc[rr];
            }
        }
    }
}

// ============ P2: streaming score + max (no MFMA, no barriers in hot loop) ============
// Block: one b, 256 tokens. Wave w: tokens [w*64,(w+1)*64), lane -> 2 o-cols.
__launch_bounds__(256, 8)
__global__ void score_max(const int* __restrict__ x,
                          const short* __restrict__ D,
                          const float* __restrict__ r,
                          const float* __restrict__ att_b_p,
                          const float* __restrict__ cnn_b,
                          float* __restrict__ out) {
    __shared__ int   sh_x[260];
    __shared__ float sh_sc[256];
    __shared__ float sh_red[4][128];

    const int tid  = threadIdx.x;
    const int lane = tid & 63;
    const int w    = tid >> 6;
    const int b    = blockIdx.y;
    const int t0   = blockIdx.x * 256;

    for (int i = tid; i < 260; i += 256) {
        int t = t0 + i - PAD_;
        sh_x[i] = (t >= 0 && t < T_) ? x[b * T_ + t] : -1;
    }
    __syncthreads();

    // scores: one token per thread, 5 gathered fp32 taps
    {
        float s = att_b_p[0];
        #pragma unroll
        for (int k = 0; k < WIN_; k++) {
            int v = sh_x[tid + k];
            if (v >= 0) s += r[(size_t)v * 8 + k];
        }
        sh_sc[tid] = 1.0f / (1.0f + __expf(-s));
    }
    __syncthreads();

    // streaming max over 64 tokens, 8-deep load batches
    float mm0 = -INFINITY, mm1 = -INFINITY;
    const int base_t = w * 64;
    for (int i0 = 0; i0 < 64; i0 += 8) {
        unsigned u[8];
        float sc8[8];
        #pragma unroll
        for (int j = 0; j < 8; j++) {
            int tok = base_t + i0 + j;
            int v   = sh_x[tok + PAD_];          // always valid
            sc8[j]  = sh_sc[tok];
            u[j]    = *(const unsigned*)(D + (size_t)v * E_ + lane * 2);
        }
        #pragma unroll
        for (int j = 0; j < 8; j++) {
            float lo = __uint_as_float(u[j] << 16);          // col 2*lane
            float hi = __uint_as_float(u[j] & 0xFFFF0000u);  // col 2*lane+1
            mm0 = fmaxf(mm0, sc8[j] * lo);
            mm1 = fmaxf(mm1, sc8[j] * hi);
        }
    }

    sh_red[w][lane * 2]     = mm0;
    sh_red[w][lane * 2 + 1] = mm1;
    __syncthreads();
    if (tid < 128) {
        float m = fmaxf(fmaxf(sh_red[0][tid], sh_red[1][tid]),
                        fmaxf(sh_red[2][tid], sh_red[3][tid]));
        atomicMaxFloat(&out[b * OC_ + tid], tanhf(m + cnn_b[tid]));
    }
}

// ============ fallback (small ws): monolithic fp32-gather version ============
__global__ void prep_small(const float* __restrict__ cnn_w, const float* __restrict__ att_w,
                           short* __restrict__ wsw, short* __restrict__ wsatt) {
    int i = blockIdx.x * 256 + threadIdx.x;
    if (i < OC_ * E_)  wsw[i]   = f2bf(cnn_w[i]);
    if (i < WIN_ * E_) wsatt[i] = f2bf(att_w[i]);
}

__launch_bounds__(256, 4)
__global__ void fallback_main(const int* __restrict__ x,
                              const float* __restrict__ emb,
                              const float* __restrict__ att_b_p,
                              const short* __restrict__ wsw,
                              const short* __restrict__ wsatt,
                              const float* __restrict__ cnn_b,
                              float* __restrict__ out) {
    __shared__ short sh_a[ROWS * ASTR];
    __shared__ short sh_att[16 * ASTR];
    __shared__ float sh_r[ROWS * 8];
    __shared__ float sh_score[TT];
    __shared__ int   sh_idx[8 * ROWS];

    const int tid  = threadIdx.x;
    const int lane = tid & 63;
    const int w    = tid >> 6;
    const int b    = blockIdx.y;
    const int t0   = blockIdx.x * (8 * TT);
    const int l15  = lane & 15;
    const int quad = lane >> 4;
    const int rbase = tid >> 4;
    const int c     = tid & 15;

    for (int i = tid; i < 8 * ROWS; i += 256) {
        int tile = i / ROWS, row = i - tile * ROWS;
        int t = t0 + tile * TT + row - PAD_;
        sh_idx[i] = (row < REAL_ROWS && t >= 0 && t < T_) ? x[b * T_ + t] : -1;
    }
    {
        int o = tid >> 4, cc = tid & 15;
        short8 v = (short8){0,0,0,0,0,0,0,0};
        if (o < WIN_) v = *(const short8*)(wsatt + o * E_ + cc * 8);
        *(short8*)(&sh_att[o * ASTR + cc * 8]) = v;
    }
    short8 Bf[2][4];
    #pragma unroll
    for (int j = 0; j < 2; j++)
        #pragma unroll
        for (int ks = 0; ks < 4; ks++)
            Bf[j][ks] = *(const short8*)(wsw + (size_t)(w * 32 + j * 16 + l15) * E_ + ks * 32 + quad * 8);
    __syncthreads();

    short8 g[5];
    #pragma unroll
    for (int k = 0; k < 5; k++) {
        int idx = sh_idx[rbase + 16 * k];
        short8 v = (short8){0,0,0,0,0,0,0,0};
        if (idx >= 0) {
            const float4* p = (const float4*)(emb + (size_t)idx * E_ + c * 8);
            float4 p0 = p[0], p1 = p[1];
            v = (short8){ f2bf(p0.x), f2bf(p0.y), f2bf(p0.z), f2bf(p0.w),
                          f2bf(p1.x), f2bf(p1.y), f2bf(p1.z), f2bf(p1.w) };
        }
        g[k] = v;
    }
    #pragma unroll
    for (int k = 0; k < 5; k++)
        *(short8*)(&sh_a[(rbase + 16 * k) * ASTR + c * 8]) = g[k];
    __syncthreads();

    const float attb = att_b_p[0];
    float mm[2] = { -INFINITY, -INFINITY };

    for (int it = 0; it < 8; it++) {
        for (int mt = w; mt < 5; mt += 4) {
            floatx4 acc = (floatx4){0.f, 0.f, 0.f, 0.f};
            #pragma unroll
            for (int ks = 0; ks < 4; ks++) {
                short8 a  = *(const short8*)(&sh_a[(mt * 16 + l15) * ASTR + ks * 32 + quad * 8]);
                short8 bs = *(const short8*)(&sh_att[l15 * ASTR + ks * 32 + quad * 8]);
                acc = __builtin_amdgcn_mfma_f32_16x16x32_bf16(a, bs, acc, 0, 0, 0);
            }
            if (l15 < 8) {
                #pragma unroll
                for (int r = 0; r < 4; r++)
                    sh_r[(mt * 16 + quad * 4 + r) * 8 + l15] = acc[r];
            }
        }
        __syncthreads();

        if (it + 1 < 8) {
            const int* idxp = &sh_idx[(it + 1) * ROWS];
            #pragma unroll
            for (int k = 0; k < 5; k++) {
                int idx = idxp[rbase + 16 * k];
                short8 v = (short8){0,0,0,0,0,0,0,0};
                if (idx >= 0) {
                    const float4* p = (const float4*)(emb + (size_t)idx * E_ + c * 8);
                    float4 p0 = p[0], p1 = p[1];
                    v = (short8){ f2bf(p0.x), f2bf(p0.y), f2bf(p0.z), f2bf(p0.w),
                                  f2bf(p1.x), f2bf(p1.y), f2bf(p1.z), f2bf(p1.w) };
                }
                g[k] = v;
            }
        }

        if (tid < TT) {
            float s = attb;
            #pragma unroll
            for (int k = 0; k < WIN_; k++) s += sh_r[(tid + k) * 8 + k];
            sh_score[tid] = 1.0f / (1.0f + __expf(-s));
        }

        floatx4 acc[4][2];
        #pragma unroll
        for (int i = 0; i < 4; i++)
            #pragma unroll
            for (int j = 0; j < 2; j++) acc[i][j] = (floatx4){0.f, 0.f, 0.f, 0.f};
        #pragma unroll
        for (int ks = 0; ks < 4; ks++) {
            int ko = ks * 32 + quad * 8;
            #pragma unroll
            for (int i = 0; i < 4; i++) {
                short8 ai = *(const short8*)(&sh_a[(PAD_ + i * 16 + l15) * ASTR + ko]);
                acc[i][0] = __builtin_amdgcn_mfma_f32_16x16x32_bf16(ai, Bf[0][ks], acc[i][0], 0, 0, 0);
                acc[i][1] = __builtin_amdgcn_mfma_f32_16x16x32_bf16(ai, Bf[1][ks], acc[i][1], 0, 0, 0);
            }
        }
        __syncthreads();

        #pragma unroll
        for (int i = 0; i < 4; i++) {
            #pragma unroll
            for (int r = 0; r < 4; r++) {
                float sc = sh_score[i * 16 + quad * 4 + r];
                mm[0] = fmaxf(mm[0], sc * acc[i][0][r]);
                mm[1] = fmaxf(mm[1], sc * acc[i][1][r]);
            }
        }

        if (it + 1 < 8) {
            #pragma unroll
            for (int k = 0; k < 5; k++)
                *(short8*)(&sh_a[(rbase + 16 * k) * ASTR + c * 8]) = g[k];
            __syncthreads();
        }
    }

    #pragma unroll
    for (int j = 0; j < 2; j++) {
        float m = mm[j];
        m = fmaxf(m, __shfl_xor(m, 16));
        m = fmaxf(m, __shfl_xor(m, 32));
        if (lane < 16) {
            int o = w * 32 + j * 16 + lane;
            atomicMaxFloat(&out[b * OC_ + o], tanhf(m + cnn_b[o]));
        }
    }
}

extern "C" void kernel_launch(void* const* d_in, const int* in_sizes, int n_in,
                              void* d_out, int out_size, void* d_ws, size_t ws_size,
                              hipStream_t stream) {
    const int*   x     = (const int*)d_in[0];
    const float* emb   = (const float*)d_in[1];
    const float* att_w = (const float*)d_in[2];
    const float* att_b = (const float*)d_in[3];
    const float* cnn_w = (const float*)d_in[4];
    const float* cnn_b = (const float*)d_in[5];
    float* out = (float*)d_out;

    hipMemsetAsync(d_out, 0xFF, (size_t)B_ * OC_ * sizeof(float), stream);

    const size_t d_elems = (size_t)VOCAB1 * E_;     // bf16 count
    const size_t r_elems = (size_t)VOCAB1 * 8;      // fp32 count
    const size_t need = d_elems * 2 + r_elems * 4 + 64;

    if (ws_size >= need) {
        short* Dt = (short*)d_ws;
        float* rt = (float*)(Dt + d_elems);
        build_tables<<<(VOCAB1 + VROWS - 1) / VROWS, 256, 0, stream>>>(emb, cnn_w, att_w, Dt, rt);
        dim3 grid(T_ / 256, B_);                     // (8, 256) = 2048 blocks
        score_max<<<grid, 256, 0, stream>>>(x, Dt, rt, att_b, cnn_b, out);
    } else {
        short* ws_w   = (short*)d_ws;
        short* ws_att = ws_w + OC_ * E_;
        prep_small<<<16, 256, 0, stream>>>(cnn_w, att_w, ws_w, ws_att);
        dim3 grid(T_ / (8 * TT), B_);
        fallback_main<<<grid, 256, 0, stream>>>(x, emb, att_b, ws_w, ws_att, cnn_b, out);
    }
}